// Round 5
// baseline (3696.989 us; speedup 1.0000x reference)
//
#include <hip/hip_runtime.h>
#include <math.h>

#define NROWS 8192
#define DIM   512
#define NCLS  10
#define GT    4        // 128-wide tile grid (4x4)
#define GPAIR 10       // lower-triangle 128-tile pairs
#define NMAT  32

// ---------------------------------------------------------------- counts/lists
__global__ __launch_bounds__(256) void k_count(const int* __restrict__ label,
                                               int* __restrict__ counts,
                                               int* __restrict__ lists) {
    __shared__ int hist[NCLS];
    __shared__ int base[NCLS];
    __shared__ int lofs[NCLS];
    int tid = threadIdx.x;
    int i = blockIdx.x * 256 + tid;
    if (tid < NCLS) { hist[tid] = 0; lofs[tid] = 0; }
    __syncthreads();
    int c = label[i];
    atomicAdd(&hist[c], 1);
    __syncthreads();
    if (tid < NCLS) base[tid] = atomicAdd(&counts[tid], hist[tid]);
    __syncthreads();
    int lpos = atomicAdd(&lofs[c], 1);
    lists[(size_t)c * NROWS + base[c] + lpos] = i;
}

// ---------------------------------------------------------------- per-class Grams
// G packed: [tensor(2)][class(10)][pair(10)][128*128]; lower pairs ti>=tj over 4x4.
// 512 threads = 2 k-groups of 256; conflict-free split-column fragments.
__global__ __launch_bounds__(512) void k_gram(const float* __restrict__ Z,
                                              const float* __restrict__ Zb,
                                              const int* __restrict__ counts,
                                              const int* __restrict__ lists,
                                              float* __restrict__ G) {
    int pt = blockIdx.x;
    int c  = blockIdx.y;
    int tz = blockIdx.z;
    int ti = 0, tj = 0;
    { int p = pt;
      for (int r = 0; r < GT; ++r) { if (p <= r) { ti = r; tj = p; break; } p -= (r + 1); } }
    bool diag = (ti == tj);

    const float* __restrict__ src = tz ? Zb : Z;
    float* __restrict__ Gout = G + (((size_t)tz * NCLS + c) * GPAIR + pt) * 16384;
    int cnt = counts[c];
    const int* __restrict__ list = lists + (size_t)c * NROWS;

    __shared__ float As[2][16][132];
    __shared__ float Bs[2][16][132];
    int tid = threadIdx.x;
    int gid = tid >> 8;          // k-group
    int t   = tid & 255;
    int tx = t & 15, ty = t >> 4;
    int srow = t >> 4, sc4 = t & 15;   // staging: row 0..15, f4-cols sc4 and 16+sc4

    float acc[8][8];
    #pragma unroll
    for (int r = 0; r < 8; ++r)
        #pragma unroll
        for (int s = 0; s < 8; ++s) acc[r][s] = 0.f;

    for (int base0 = 0; base0 < cnt; base0 += 32) {
        int gr = base0 + gid * 16 + srow;
        float4 va0 = make_float4(0.f, 0.f, 0.f, 0.f), va1 = va0, vb0 = va0, vb1 = va0;
        if (gr < cnt) {
            int ridx = list[gr];
            const float* __restrict__ rp = src + (size_t)ridx * DIM;
            va0 = *(const float4*)&rp[ti * 128 + sc4 * 4];
            va1 = *(const float4*)&rp[ti * 128 + 64 + sc4 * 4];
            if (!diag) {
                vb0 = *(const float4*)&rp[tj * 128 + sc4 * 4];
                vb1 = *(const float4*)&rp[tj * 128 + 64 + sc4 * 4];
            }
        }
        *(float4*)&As[gid][srow][sc4 * 4]      = va0;
        *(float4*)&As[gid][srow][64 + sc4 * 4] = va1;
        if (!diag) {
            *(float4*)&Bs[gid][srow][sc4 * 4]      = vb0;
            *(float4*)&Bs[gid][srow][64 + sc4 * 4] = vb1;
        }
        __syncthreads();

        const float (*__restrict__ Ap)[132] = As[gid];
        const float (*__restrict__ Bp)[132] = diag ? As[gid] : Bs[gid];
        #pragma unroll
        for (int kk = 0; kk < 16; ++kk) {
            float a[8], b[8];
            *(float4*)&a[0] = *(const float4*)&Ap[kk][ty * 4];
            *(float4*)&a[4] = *(const float4*)&Ap[kk][64 + ty * 4];
            *(float4*)&b[0] = *(const float4*)&Bp[kk][tx * 4];
            *(float4*)&b[4] = *(const float4*)&Bp[kk][64 + tx * 4];
            #pragma unroll
            for (int r = 0; r < 8; ++r)
                #pragma unroll
                for (int s = 0; s < 8; ++s)
                    acc[r][s] += a[r] * b[s];
        }
        __syncthreads();
    }

    // reduce group1 into group0 through LDS
    float* red = (float*)&As[0][0][0];
    #pragma unroll 1
    for (int r = 0; r < 8; ++r) {
        __syncthreads();
        if (gid == 1) {
            #pragma unroll
            for (int s = 0; s < 8; ++s) red[t * 8 + s] = acc[r][s];
        }
        __syncthreads();
        if (gid == 0) {
            #pragma unroll
            for (int s = 0; s < 8; ++s) acc[r][s] += red[t * 8 + s];
        }
    }
    if (gid == 0) {
        #pragma unroll
        for (int r = 0; r < 8; ++r) {
            int row = (r < 4) ? (ty * 4 + r) : (64 + ty * 4 + r - 4);
            float4 v0 = make_float4(acc[r][0], acc[r][1], acc[r][2], acc[r][3]);
            float4 v1 = make_float4(acc[r][4], acc[r][5], acc[r][6], acc[r][7]);
            *(float4*)&Gout[(size_t)row * 128 + tx * 4]      = v0;
            *(float4*)&Gout[(size_t)row * 128 + 64 + tx * 4] = v1;
        }
    }
}

// ---------------------------------------------------------------- assemble (lower tiles only)
__global__ __launch_bounds__(256) void k_assemble(const float* __restrict__ G,
                                                  const int* __restrict__ counts,
                                                  float* __restrict__ A) {
    int pt = blockIdx.x;
    int m  = blockIdx.y;
    int ti = 0, tj = 0;
    { int p = pt;
      for (int r = 0; r < GT; ++r) { if (p <= r) { ti = r; tj = p; break; } p -= (r + 1); } }

    const size_t TILE = 16384;
    const float* __restrict__ Gz  = G;
    const float* __restrict__ Gzb = G + (size_t)NCLS * GPAIR * TILE;
    float* __restrict__ Am = A + (size_t)m * DIM * DIM;
    int tid = threadIdx.x;

    int mode; int c; float sc;
    if (m < 10)      { mode = 0; c = m;      sc = 1024.f / ((float)counts[c] + 1e-8f); }
    else if (m < 20) { mode = 1; c = m - 10; sc = 1024.f / ((float)counts[c] + 1e-8f); }
    else if (m < 30) { mode = 2; c = m - 20; sc = 512.f / (float)counts[c]; }
    else             { mode = (m == 30) ? 3 : 4; c = 0; sc = 0.125f; }

    #pragma unroll 1
    for (int h = 0; h < 16; ++h) {
        int id = h * 256 + tid;
        int row = id >> 5, c4 = id & 31;
        size_t off = (size_t)row * 128 + c4 * 4;
        float4 g = make_float4(0.f, 0.f, 0.f, 0.f);
        if (mode == 0) {
            g = *(const float4*)&Gz[((size_t)c * GPAIR + pt) * TILE + off];
        } else if (mode == 1) {
            g = *(const float4*)&Gzb[((size_t)c * GPAIR + pt) * TILE + off];
        } else if (mode == 2) {
            float4 a = *(const float4*)&Gz [((size_t)c * GPAIR + pt) * TILE + off];
            float4 b = *(const float4*)&Gzb[((size_t)c * GPAIR + pt) * TILE + off];
            g.x = a.x + b.x; g.y = a.y + b.y; g.z = a.z + b.z; g.w = a.w + b.w;
        } else if (mode == 3) {
            for (int cc = 0; cc < NCLS; ++cc) {
                float4 t = *(const float4*)&Gz[((size_t)cc * GPAIR + pt) * TILE + off];
                g.x += t.x; g.y += t.y; g.z += t.z; g.w += t.w;
            }
        } else {
            for (int cc = 0; cc < NCLS; ++cc) {
                float4 t = *(const float4*)&Gzb[((size_t)cc * GPAIR + pt) * TILE + off];
                g.x += t.x; g.y += t.y; g.z += t.z; g.w += t.w;
            }
        }
        g.x *= sc; g.y *= sc; g.z *= sc; g.w *= sc;
        if (ti == tj) {
            int cb = c4 * 4;
            if (row == cb)     g.x += 1.f;
            if (row == cb + 1) g.y += 1.f;
            if (row == cb + 2) g.z += 1.f;
            if (row == cb + 3) g.w += 1.f;
        }
        *(float4*)&Am[(size_t)(ti * 128 + row) * DIM + tj * 128 + c4 * 4] = g;
    }
}

// ---------------------------------------------------------------- fused panel step
// Grid (pairs, NMAT). Every block: load+factor the 64x64 diag (redundant, deterministic),
// trsm its own two 64-row chunks (row/thread) into LDS, syrk its 64x64 output tile.
// pair==0 block also adds the panel's logdet. p==7 (K==0): fact+logdet only.
__global__ __launch_bounds__(256) void k_panel(float* __restrict__ A,
                                               float* __restrict__ ld,
                                               int p) {
    int K = 7 - p;
    int m    = blockIdx.y;
    int pair = blockIdx.x;
    int a = 0, b = 0;
    { int q = pair;
      for (int r = 0; r < 8; ++r) { if (q <= r) { a = r; b = q; break; } q -= (r + 1); } }

    float* __restrict__ Am = A + (size_t)m * DIM * DIM;
    int col0 = p * 64, col1 = col0 + 64;
    int tid = threadIdx.x;

    __shared__ float Dl[64][65];
    __shared__ float dinv[64];
    __shared__ float Ta[64][68];
    __shared__ float Tb[64][68];

    for (int h = tid; h < 1024; h += 256) {
        int r = h >> 4, c4 = h & 15;
        *(float4*)&Dl[r][c4 * 4] = *(const float4*)&Am[(size_t)(col0 + r) * DIM + col0 + c4 * 4];
    }
    __syncthreads();

    if (tid < 64) {
        int lane = tid;
        float row_[64];
        #pragma unroll
        for (int j = 0; j < 64; ++j) row_[j] = Dl[lane][j];
        float dval = 1.f;
        #pragma unroll
        for (int k = 0; k < 64; ++k) {
            float piv = __shfl(row_[k], k);
            float s = 1.0f / sqrtf(piv);
            float lik = row_[k] * s;
            dval = (lane == k) ? lik : dval;
            row_[k] = lik;
            #pragma unroll
            for (int j = k + 1; j < 64; ++j)
                row_[j] -= lik * __shfl(lik, j);
        }
        #pragma unroll
        for (int j = 0; j < 64; ++j) Dl[lane][j] = row_[j];
        dinv[lane] = 1.f / dval;
        if (pair == 0) {
            float v = 2.f * logf(dval);
            #pragma unroll
            for (int off = 32; off > 0; off >>= 1) v += __shfl_down(v, off);
            if (lane == 0) atomicAdd(&ld[m], v);
        }
    }
    __syncthreads();
    if (K == 0) return;

    // trsm: chunk 0 -> rows of tile a, chunk 1 -> rows of tile b (skip if b==a)
    int chunk = tid >> 6;
    if (chunk == 0 || (chunk == 1 && b != a)) {
        int which = chunk ? b : a;
        int r = tid & 63;
        const float* __restrict__ Brow = Am + (size_t)(col1 + which * 64 + r) * DIM + col0;
        float (*__restrict__ Tp)[68] = chunk ? Tb : Ta;
        float t[64];
        #pragma unroll
        for (int i = 0; i < 64; ++i) {
            float acc0 = Brow[i], acc1 = 0.f;
            int mm = 0;
            #pragma unroll
            for (; mm + 1 < i; mm += 2) {
                acc0 -= t[mm]     * Dl[i][mm];
                acc1 -= t[mm + 1] * Dl[i][mm + 1];
            }
            if (mm < i) acc0 -= t[mm] * Dl[i][mm];
            t[i] = (acc0 + acc1) * dinv[i];
            Tp[i][r] = t[i];
        }
    }
    __syncthreads();

    // syrk: C[i][j] -= sum_k Ta[k][i] * Tb[k][j]
    int tx = tid & 15, ty = tid >> 4;
    float acc[4][4];
    #pragma unroll
    for (int r = 0; r < 4; ++r)
        #pragma unroll
        for (int s = 0; s < 4; ++s) acc[r][s] = 0.f;
    const float (*__restrict__ TB)[68] = (b == a) ? Ta : Tb;
    #pragma unroll 8
    for (int kk = 0; kk < 64; ++kk) {
        float av[4], bv[4];
        *(float4*)av = *(const float4*)&Ta[kk][ty * 4];
        *(float4*)bv = *(const float4*)&TB[kk][tx * 4];
        #pragma unroll
        for (int r = 0; r < 4; ++r)
            #pragma unroll
            for (int s = 0; s < 4; ++s)
                acc[r][s] += av[r] * bv[s];
    }
    #pragma unroll
    for (int r = 0; r < 4; ++r) {
        size_t off = (size_t)(col1 + a * 64 + ty * 4 + r) * DIM + col1 + b * 64 + tx * 4;
        float4 cv = *(float4*)&Am[off];
        cv.x -= acc[r][0]; cv.y -= acc[r][1]; cv.z -= acc[r][2]; cv.w -= acc[r][3];
        *(float4*)&Am[off] = cv;
    }
}

// ---------------------------------------------------------------- finalize
__global__ void k_final(const float* __restrict__ ld,
                        const int* __restrict__ counts,
                        float* __restrict__ out) {
    if (threadIdx.x == 0 && blockIdx.x == 0) {
        float disc_z  = 0.5f * ld[30];
        float disc_zb = 0.5f * ld[31];
        float comp_z = 0.f, comp_zb = 0.f, sum_ldz = 0.f, sum_ldzb = 0.f, item = 0.f;
        for (int c = 0; c < NCLS; ++c) {
            float trPi = (float)counts[c] + 1e-8f;
            float s = trPi / (2.f * (float)NROWS);
            comp_z  += s * ld[c];
            comp_zb += s * ld[10 + c];
            sum_ldz  += ld[c];
            sum_ldzb += ld[10 + c];
            item += 0.5f * ld[20 + c];
        }
        float term3 = item - 0.25f * sum_ldz - 0.25f * sum_ldzb;
        float z_total  = -(disc_z - comp_z);
        float zb_total = -(disc_zb - comp_zb);
        float errD = -((disc_z - comp_z) + (disc_zb - comp_zb) + term3);
        out[0] = errD; out[1] = z_total; out[2] = zb_total; out[3] = term3;
    }
}

// ---------------------------------------------------------------- launch
extern "C" void kernel_launch(void* const* d_in, const int* in_sizes, int n_in,
                              void* d_out, int out_size, void* d_ws, size_t ws_size,
                              hipStream_t stream) {
    (void)in_sizes; (void)n_in; (void)out_size; (void)ws_size;
    const float* Z     = (const float*)d_in[0];
    const float* Zb    = (const float*)d_in[1];
    const int*   label = (const int*)d_in[2];

    char* ws = (char*)d_ws;
    int*   counts = (int*)ws;                                    // 40 B
    float* ld     = (float*)(ws + 64);                           // 128 B
    int*   lists  = (int*)(ws + 256);                            // 320 KiB
    float* G      = (float*)(ws + 256 + (size_t)NCLS * NROWS * 4);   // 12.5 MiB
    float* A      = G + (size_t)2 * NCLS * GPAIR * 16384;        // 32 MiB
    float* out    = (float*)d_out;

    hipMemsetAsync(ws, 0, 256, stream);
    k_count<<<NROWS / 256, 256, 0, stream>>>(label, counts, lists);
    k_gram<<<dim3(GPAIR, NCLS, 2), 512, 0, stream>>>(Z, Zb, counts, lists, G);
    k_assemble<<<dim3(GPAIR, NMAT), 256, 0, stream>>>(G, counts, A);
    for (int p = 0; p < 8; ++p) {
        int K = 7 - p;
        int pairs = (K > 0) ? K * (K + 1) / 2 : 1;
        k_panel<<<dim3(pairs, NMAT), 256, 0, stream>>>(A, ld, p);
    }
    k_final<<<1, 64, 0, stream>>>(ld, counts, out);
}

// Round 6
// 601.585 us; speedup vs baseline: 6.1454x; 6.1454x over previous
//
#include <hip/hip_runtime.h>
#include <math.h>

#define NROWS 8192
#define DIM   512
#define NCLS  10
#define GT    4        // 128-wide tile grid (4x4)
#define GPAIR 10       // lower-triangle 128-tile pairs
#define NMAT  32

// ---------------------------------------------------------------- counts/lists
__global__ __launch_bounds__(256) void k_count(const int* __restrict__ label,
                                               int* __restrict__ counts,
                                               int* __restrict__ lists) {
    __shared__ int hist[NCLS];
    __shared__ int base[NCLS];
    __shared__ int lofs[NCLS];
    int tid = threadIdx.x;
    int i = blockIdx.x * 256 + tid;
    if (tid < NCLS) { hist[tid] = 0; lofs[tid] = 0; }
    __syncthreads();
    int c = label[i];
    atomicAdd(&hist[c], 1);
    __syncthreads();
    if (tid < NCLS) base[tid] = atomicAdd(&counts[tid], hist[tid]);
    __syncthreads();
    int lpos = atomicAdd(&lofs[c], 1);
    lists[(size_t)c * NROWS + base[c] + lpos] = i;
}

// ---------------------------------------------------------------- per-class Grams
// G packed: [tensor(2)][class(10)][pair(10)][128*128]; lower pairs ti>=tj over 4x4.
// 512 threads = 2 k-groups of 256; conflict-free split-column fragments.
__global__ __launch_bounds__(512) void k_gram(const float* __restrict__ Z,
                                              const float* __restrict__ Zb,
                                              const int* __restrict__ counts,
                                              const int* __restrict__ lists,
                                              float* __restrict__ G) {
    int pt = blockIdx.x;
    int c  = blockIdx.y;
    int tz = blockIdx.z;
    int ti = 0, tj = 0;
    { int p = pt;
      for (int r = 0; r < GT; ++r) { if (p <= r) { ti = r; tj = p; break; } p -= (r + 1); } }
    bool diag = (ti == tj);

    const float* __restrict__ src = tz ? Zb : Z;
    float* __restrict__ Gout = G + (((size_t)tz * NCLS + c) * GPAIR + pt) * 16384;
    int cnt = counts[c];
    const int* __restrict__ list = lists + (size_t)c * NROWS;

    __shared__ float As[2][16][132];
    __shared__ float Bs[2][16][132];
    int tid = threadIdx.x;
    int gid = tid >> 8;          // k-group
    int t   = tid & 255;
    int tx = t & 15, ty = t >> 4;
    int srow = t >> 4, sc4 = t & 15;   // staging: row 0..15, f4-cols sc4 and 16+sc4

    float acc[8][8];
    #pragma unroll
    for (int r = 0; r < 8; ++r)
        #pragma unroll
        for (int s = 0; s < 8; ++s) acc[r][s] = 0.f;

    for (int base0 = 0; base0 < cnt; base0 += 32) {
        int gr = base0 + gid * 16 + srow;
        float4 va0 = make_float4(0.f, 0.f, 0.f, 0.f), va1 = va0, vb0 = va0, vb1 = va0;
        if (gr < cnt) {
            int ridx = list[gr];
            const float* __restrict__ rp = src + (size_t)ridx * DIM;
            va0 = *(const float4*)&rp[ti * 128 + sc4 * 4];
            va1 = *(const float4*)&rp[ti * 128 + 64 + sc4 * 4];
            if (!diag) {
                vb0 = *(const float4*)&rp[tj * 128 + sc4 * 4];
                vb1 = *(const float4*)&rp[tj * 128 + 64 + sc4 * 4];
            }
        }
        *(float4*)&As[gid][srow][sc4 * 4]      = va0;
        *(float4*)&As[gid][srow][64 + sc4 * 4] = va1;
        if (!diag) {
            *(float4*)&Bs[gid][srow][sc4 * 4]      = vb0;
            *(float4*)&Bs[gid][srow][64 + sc4 * 4] = vb1;
        }
        __syncthreads();

        const float (*__restrict__ Ap)[132] = As[gid];
        const float (*__restrict__ Bp)[132] = diag ? As[gid] : Bs[gid];
        #pragma unroll
        for (int kk = 0; kk < 16; ++kk) {
            float a[8], b[8];
            *(float4*)&a[0] = *(const float4*)&Ap[kk][ty * 4];
            *(float4*)&a[4] = *(const float4*)&Ap[kk][64 + ty * 4];
            *(float4*)&b[0] = *(const float4*)&Bp[kk][tx * 4];
            *(float4*)&b[4] = *(const float4*)&Bp[kk][64 + tx * 4];
            #pragma unroll
            for (int r = 0; r < 8; ++r)
                #pragma unroll
                for (int s = 0; s < 8; ++s)
                    acc[r][s] += a[r] * b[s];
        }
        __syncthreads();
    }

    // reduce group1 into group0 through LDS.
    // MUST be fully unrolled: a runtime index into acc[][] forces the whole
    // accumulator into scratch (rule #20) — that was R4's 6x regression.
    float* red = (float*)&As[0][0][0];
    #pragma unroll
    for (int r = 0; r < 8; ++r) {
        __syncthreads();
        if (gid == 1) {
            #pragma unroll
            for (int s = 0; s < 8; ++s) red[t * 8 + s] = acc[r][s];
        }
        __syncthreads();
        if (gid == 0) {
            #pragma unroll
            for (int s = 0; s < 8; ++s) acc[r][s] += red[t * 8 + s];
        }
    }
    if (gid == 0) {
        #pragma unroll
        for (int r = 0; r < 8; ++r) {
            int row = (r < 4) ? (ty * 4 + r) : (64 + ty * 4 + r - 4);
            float4 v0 = make_float4(acc[r][0], acc[r][1], acc[r][2], acc[r][3]);
            float4 v1 = make_float4(acc[r][4], acc[r][5], acc[r][6], acc[r][7]);
            *(float4*)&Gout[(size_t)row * 128 + tx * 4]      = v0;
            *(float4*)&Gout[(size_t)row * 128 + 64 + tx * 4] = v1;
        }
    }
}

// ---------------------------------------------------------------- assemble (lower tiles only)
__global__ __launch_bounds__(256) void k_assemble(const float* __restrict__ G,
                                                  const int* __restrict__ counts,
                                                  float* __restrict__ A) {
    int pt = blockIdx.x;
    int m  = blockIdx.y;
    int ti = 0, tj = 0;
    { int p = pt;
      for (int r = 0; r < GT; ++r) { if (p <= r) { ti = r; tj = p; break; } p -= (r + 1); } }

    const size_t TILE = 16384;
    const float* __restrict__ Gz  = G;
    const float* __restrict__ Gzb = G + (size_t)NCLS * GPAIR * TILE;
    float* __restrict__ Am = A + (size_t)m * DIM * DIM;
    int tid = threadIdx.x;

    int mode; int c; float sc;
    if (m < 10)      { mode = 0; c = m;      sc = 1024.f / ((float)counts[c] + 1e-8f); }
    else if (m < 20) { mode = 1; c = m - 10; sc = 1024.f / ((float)counts[c] + 1e-8f); }
    else if (m < 30) { mode = 2; c = m - 20; sc = 512.f / (float)counts[c]; }
    else             { mode = (m == 30) ? 3 : 4; c = 0; sc = 0.125f; }

    #pragma unroll 1
    for (int h = 0; h < 16; ++h) {
        int id = h * 256 + tid;
        int row = id >> 5, c4 = id & 31;
        size_t off = (size_t)row * 128 + c4 * 4;
        float4 g = make_float4(0.f, 0.f, 0.f, 0.f);
        if (mode == 0) {
            g = *(const float4*)&Gz[((size_t)c * GPAIR + pt) * TILE + off];
        } else if (mode == 1) {
            g = *(const float4*)&Gzb[((size_t)c * GPAIR + pt) * TILE + off];
        } else if (mode == 2) {
            float4 a = *(const float4*)&Gz [((size_t)c * GPAIR + pt) * TILE + off];
            float4 b = *(const float4*)&Gzb[((size_t)c * GPAIR + pt) * TILE + off];
            g.x = a.x + b.x; g.y = a.y + b.y; g.z = a.z + b.z; g.w = a.w + b.w;
        } else if (mode == 3) {
            for (int cc = 0; cc < NCLS; ++cc) {
                float4 t = *(const float4*)&Gz[((size_t)cc * GPAIR + pt) * TILE + off];
                g.x += t.x; g.y += t.y; g.z += t.z; g.w += t.w;
            }
        } else {
            for (int cc = 0; cc < NCLS; ++cc) {
                float4 t = *(const float4*)&Gzb[((size_t)cc * GPAIR + pt) * TILE + off];
                g.x += t.x; g.y += t.y; g.z += t.z; g.w += t.w;
            }
        }
        g.x *= sc; g.y *= sc; g.z *= sc; g.w *= sc;
        if (ti == tj) {
            int cb = c4 * 4;
            if (row == cb)     g.x += 1.f;
            if (row == cb + 1) g.y += 1.f;
            if (row == cb + 2) g.z += 1.f;
            if (row == cb + 3) g.w += 1.f;
        }
        *(float4*)&Am[(size_t)(ti * 128 + row) * DIM + tj * 128 + c4 * 4] = g;
    }
}

// ---------------------------------------------------------------- fused panel step
// Grid (pairs, NMAT). Every block: load+factor the 64x64 diag (redundant, deterministic),
// trsm its own two 64-row chunks (row/thread) into LDS, syrk its 64x64 output tile.
// pair==0 block also adds the panel's logdet. p==7 (K==0): fact+logdet only.
__global__ __launch_bounds__(256) void k_panel(float* __restrict__ A,
                                               float* __restrict__ ld,
                                               int p) {
    int K = 7 - p;
    int m    = blockIdx.y;
    int pair = blockIdx.x;
    int a = 0, b = 0;
    { int q = pair;
      for (int r = 0; r < 8; ++r) { if (q <= r) { a = r; b = q; break; } q -= (r + 1); } }

    float* __restrict__ Am = A + (size_t)m * DIM * DIM;
    int col0 = p * 64, col1 = col0 + 64;
    int tid = threadIdx.x;

    __shared__ float Dl[64][65];
    __shared__ float dinv[64];
    __shared__ float Ta[64][68];
    __shared__ float Tb[64][68];

    for (int h = tid; h < 1024; h += 256) {
        int r = h >> 4, c4 = h & 15;
        *(float4*)&Dl[r][c4 * 4] = *(const float4*)&Am[(size_t)(col0 + r) * DIM + col0 + c4 * 4];
    }
    __syncthreads();

    if (tid < 64) {
        int lane = tid;
        float row_[64];
        #pragma unroll
        for (int j = 0; j < 64; ++j) row_[j] = Dl[lane][j];
        float dval = 1.f;
        #pragma unroll
        for (int k = 0; k < 64; ++k) {
            float piv = __shfl(row_[k], k);
            float s = 1.0f / sqrtf(piv);
            float lik = row_[k] * s;
            dval = (lane == k) ? lik : dval;
            row_[k] = lik;
            #pragma unroll
            for (int j = k + 1; j < 64; ++j)
                row_[j] -= lik * __shfl(lik, j);
        }
        #pragma unroll
        for (int j = 0; j < 64; ++j) Dl[lane][j] = row_[j];
        dinv[lane] = 1.f / dval;
        if (pair == 0) {
            float v = 2.f * logf(dval);
            #pragma unroll
            for (int off = 32; off > 0; off >>= 1) v += __shfl_down(v, off);
            if (lane == 0) atomicAdd(&ld[m], v);
        }
    }
    __syncthreads();
    if (K == 0) return;

    // trsm: chunk 0 -> rows of tile a, chunk 1 -> rows of tile b (skip if b==a)
    int chunk = tid >> 6;
    if (chunk == 0 || (chunk == 1 && b != a)) {
        int which = chunk ? b : a;
        int r = tid & 63;
        const float* __restrict__ Brow = Am + (size_t)(col1 + which * 64 + r) * DIM + col0;
        float (*__restrict__ Tp)[68] = chunk ? Tb : Ta;
        float t[64];
        #pragma unroll
        for (int i = 0; i < 64; ++i) {
            float acc0 = Brow[i], acc1 = 0.f;
            int mm = 0;
            #pragma unroll
            for (; mm + 1 < i; mm += 2) {
                acc0 -= t[mm]     * Dl[i][mm];
                acc1 -= t[mm + 1] * Dl[i][mm + 1];
            }
            if (mm < i) acc0 -= t[mm] * Dl[i][mm];
            t[i] = (acc0 + acc1) * dinv[i];
            Tp[i][r] = t[i];
        }
    }
    __syncthreads();

    // syrk: C[i][j] -= sum_k Ta[k][i] * Tb[k][j]
    int tx = tid & 15, ty = tid >> 4;
    float acc[4][4];
    #pragma unroll
    for (int r = 0; r < 4; ++r)
        #pragma unroll
        for (int s = 0; s < 4; ++s) acc[r][s] = 0.f;
    const float (*__restrict__ TB)[68] = (b == a) ? Ta : Tb;
    #pragma unroll 8
    for (int kk = 0; kk < 64; ++kk) {
        float av[4], bv[4];
        *(float4*)av = *(const float4*)&Ta[kk][ty * 4];
        *(float4*)bv = *(const float4*)&TB[kk][tx * 4];
        #pragma unroll
        for (int r = 0; r < 4; ++r)
            #pragma unroll
            for (int s = 0; s < 4; ++s)
                acc[r][s] += av[r] * bv[s];
    }
    #pragma unroll
    for (int r = 0; r < 4; ++r) {
        size_t off = (size_t)(col1 + a * 64 + ty * 4 + r) * DIM + col1 + b * 64 + tx * 4;
        float4 cv = *(float4*)&Am[off];
        cv.x -= acc[r][0]; cv.y -= acc[r][1]; cv.z -= acc[r][2]; cv.w -= acc[r][3];
        *(float4*)&Am[off] = cv;
    }
}

// ---------------------------------------------------------------- finalize
__global__ void k_final(const float* __restrict__ ld,
                        const int* __restrict__ counts,
                        float* __restrict__ out) {
    if (threadIdx.x == 0 && blockIdx.x == 0) {
        float disc_z  = 0.5f * ld[30];
        float disc_zb = 0.5f * ld[31];
        float comp_z = 0.f, comp_zb = 0.f, sum_ldz = 0.f, sum_ldzb = 0.f, item = 0.f;
        for (int c = 0; c < NCLS; ++c) {
            float trPi = (float)counts[c] + 1e-8f;
            float s = trPi / (2.f * (float)NROWS);
            comp_z  += s * ld[c];
            comp_zb += s * ld[10 + c];
            sum_ldz  += ld[c];
            sum_ldzb += ld[10 + c];
            item += 0.5f * ld[20 + c];
        }
        float term3 = item - 0.25f * sum_ldz - 0.25f * sum_ldzb;
        float z_total  = -(disc_z - comp_z);
        float zb_total = -(disc_zb - comp_zb);
        float errD = -((disc_z - comp_z) + (disc_zb - comp_zb) + term3);
        out[0] = errD; out[1] = z_total; out[2] = zb_total; out[3] = term3;
    }
}

// ---------------------------------------------------------------- launch
extern "C" void kernel_launch(void* const* d_in, const int* in_sizes, int n_in,
                              void* d_out, int out_size, void* d_ws, size_t ws_size,
                              hipStream_t stream) {
    (void)in_sizes; (void)n_in; (void)out_size; (void)ws_size;
    const float* Z     = (const float*)d_in[0];
    const float* Zb    = (const float*)d_in[1];
    const int*   label = (const int*)d_in[2];

    char* ws = (char*)d_ws;
    int*   counts = (int*)ws;                                    // 40 B
    float* ld     = (float*)(ws + 64);                           // 128 B
    int*   lists  = (int*)(ws + 256);                            // 320 KiB
    float* G      = (float*)(ws + 256 + (size_t)NCLS * NROWS * 4);   // 12.5 MiB
    float* A      = G + (size_t)2 * NCLS * GPAIR * 16384;        // 32 MiB
    float* out    = (float*)d_out;

    hipMemsetAsync(ws, 0, 256, stream);
    k_count<<<NROWS / 256, 256, 0, stream>>>(label, counts, lists);
    k_gram<<<dim3(GPAIR, NCLS, 2), 512, 0, stream>>>(Z, Zb, counts, lists, G);
    k_assemble<<<dim3(GPAIR, NMAT), 256, 0, stream>>>(G, counts, A);
    for (int p = 0; p < 8; ++p) {
        int K = 7 - p;
        int pairs = (K > 0) ? K * (K + 1) / 2 : 1;
        k_panel<<<dim3(pairs, NMAT), 256, 0, stream>>>(A, ld, p);
    }
    k_final<<<1, 64, 0, stream>>>(ld, counts, out);
}